// Round 3
// baseline (158.638 us; speedup 1.0000x reference)
//
#include <hip/hip_runtime.h>

typedef unsigned short u16;
typedef __attribute__((ext_vector_type(8))) short bf16x8;
typedef __attribute__((ext_vector_type(4))) float f32x4;

#define N_MEM_C 65536
#define NNODES_C 50000
#define DDIM 128
#define LDA 136   // 128 + 8 pad (272B rows: 16B-aligned, breaks bank aliasing)
#define BM 128

// weight table layout (u16 elements):
//  WT_msg1 [128][640] @ 0        (81920)
//  WT_msg2 [128][128] @ 81920    (16384)
//  WT_hid1 [128][640] @ 98304    (81920)  rows k in [256,384) pre-folded with int_W
//  WT_hid2 [128][128] @ 180224   (16384)
#define OFF_MSG1 0
#define OFF_MSG2 81920
#define OFF_HID1 98304
#define OFF_HID2 180224
#define WT_TOTAL 196608

// Static device-global weight table (no dependence on ws_size).
__device__ __align__(16) u16 g_WT[WT_TOTAL];

__device__ __forceinline__ u16 f2bf(float f) {
  unsigned u = __float_as_uint(f);
  u += 0x7FFFu + ((u >> 16) & 1u);   // RNE
  return (u16)(u >> 16);
}
__device__ __forceinline__ unsigned pack2(float a, float b) {
  return (unsigned)f2bf(a) | ((unsigned)f2bf(b) << 16);
}
__device__ __forceinline__ float fast_tanh(float x) {
  float e = __expf(2.0f * x);
  return 1.0f - 2.0f / (e + 1.0f);   // inf-safe: e=inf -> 1, e=0 -> -1
}

// ---- prep kernel 1: transpose+convert all weights to bf16 [n][k] ----
extern "C" __global__ void prep_transpose(const float* __restrict__ msg_W1,
                                          const float* __restrict__ msg_W2,
                                          const float* __restrict__ hid_W1,
                                          const float* __restrict__ hid_W2) {
  int i = blockIdx.x * 256 + threadIdx.x;   // grid covers exactly WT_TOTAL
  float v;
  if (i < OFF_MSG2) {
    int n = i / 640, k = i % 640;
    v = msg_W1[k * 128 + n];
  } else if (i < OFF_HID1) {
    int j = i - OFF_MSG2; int n = j >> 7, k = j & 127;
    v = msg_W2[k * 128 + n];
  } else if (i < OFF_HID2) {
    int j = i - OFF_HID1; int n = j / 640, k = j % 640;
    v = hid_W1[k * 128 + n];          // k in [256,384) overwritten by prep_weff
  } else {
    int j = i - OFF_HID2; int n = j >> 7, k = j & 127;
    v = hid_W2[k * 128 + n];
  }
  g_WT[i] = f2bf(v);
}

// ---- prep kernel 2: fold int_W into hid_W1 chunk 2:  W_eff = int_W @ hid_W1[256:384,:] ----
extern "C" __global__ void prep_weff(const float* __restrict__ hid_W1,
                                     const float* __restrict__ int_W) {
  int i = blockIdx.x * 256 + threadIdx.x;   // 16384 threads
  int n = i & 127, q = i >> 7;
  float s = 0.f;
  for (int p = 0; p < 128; ++p)
    s += int_W[q * 128 + p] * hid_W1[(256 + p) * 128 + n];
  g_WT[OFF_HID1 + n * 640 + 256 + q] = f2bf(s);
}

// ---- staging helpers ----
// MODE 0: idx from LDS array; MODE 1: idx = base + r; MODE 2: idx from array, scaled per-row
template <int MODE>
__device__ __forceinline__ void stage_rows(u16 (*A)[LDA], const float* __restrict__ src,
                                           const int* idxArr, const float* scArr,
                                           int base, int maxIdx, int tid) {
#pragma unroll
  for (int it = 0; it < 4; ++it) {
    int slot = it * 256 + tid;          // 1024 slots = 128 rows x 8 (16 floats each)
    int r = slot >> 3, seg = slot & 7;
    int idx = (MODE == 1) ? (base + r) : idxArr[r];
    idx = (idx < 0) ? 0 : (idx > maxIdx ? maxIdx : idx);   // safety clamp
    float sc = (MODE == 2) ? scArr[r] : 1.0f;
    const float4* p = (const float4*)(src + (size_t)idx * DDIM + seg * 16);
    float4 f0 = p[0], f1 = p[1], f2 = p[2], f3 = p[3];
    uint4* q = (uint4*)&A[r][seg * 16];
    q[0] = make_uint4(pack2(f0.x * sc, f0.y * sc), pack2(f0.z * sc, f0.w * sc),
                      pack2(f1.x * sc, f1.y * sc), pack2(f1.z * sc, f1.w * sc));
    q[1] = make_uint4(pack2(f2.x * sc, f2.y * sc), pack2(f2.z * sc, f2.w * sc),
                      pack2(f3.x * sc, f3.y * sc), pack2(f3.z * sc, f3.w * sc));
  }
}

// FIXED: each slot covers 32 u16 (64 B) -> copy FOUR uint4, not two.
// (Rounds 1-2 NaN: half of every sW row was left uninitialized.)
__device__ __forceinline__ void stage_w(u16 (*W)[LDA], const u16* __restrict__ WT,
                                        int ldk, int koff, int tid) {
#pragma unroll
  for (int it = 0; it < 2; ++it) {
    int slot = it * 256 + tid;          // 512 slots = 128 cols x 4 (32 u16 each)
    int n = slot >> 2, seg = slot & 3;
    const uint4* p = (const uint4*)(WT + (size_t)n * ldk + koff + seg * 32);
    uint4 a = p[0], b = p[1], c = p[2], d = p[3];
    uint4* q = (uint4*)&W[n][seg * 32];
    q[0] = a; q[1] = b; q[2] = c; q[3] = d;
  }
}

// one K=128 GEMM accumulation step: acc += A_tile(128x128) @ W_tile(128x128)^T
__device__ __forceinline__ void gemm128(const u16 (*A)[LDA], const u16 (*W)[LDA],
                                        f32x4 (&acc)[4][4], int wr, int wc, int l16, int l4) {
#pragma unroll
  for (int ks = 0; ks < 4; ++ks) {
    bf16x8 av[4], bv[4];
#pragma unroll
    for (int mr = 0; mr < 4; ++mr)
      av[mr] = *(const bf16x8*)&A[wr * 64 + mr * 16 + l16][ks * 32 + l4 * 8];
#pragma unroll
    for (int nr = 0; nr < 4; ++nr)
      bv[nr] = *(const bf16x8*)&W[wc * 64 + nr * 16 + l16][ks * 32 + l4 * 8];
#pragma unroll
    for (int mr = 0; mr < 4; ++mr)
#pragma unroll
      for (int nr = 0; nr < 4; ++nr)
        acc[mr][nr] = __builtin_amdgcn_mfma_f32_16x16x32_bf16(av[mr], bv[nr], acc[mr][nr], 0, 0, 0);
  }
}

extern "C" __global__ __launch_bounds__(256, 2) void fused_flow(
    const float* __restrict__ hidden, const int* __restrict__ seen_edges,
    const int* __restrict__ memorized, const float* __restrict__ node_att,
    const float* __restrict__ hidden_uncon, const float* __restrict__ qh,
    const float* __restrict__ qr, const float* __restrict__ rel_table,
    const float* __restrict__ msg_b1, const float* __restrict__ msg_b2,
    const float* __restrict__ hid_b1, const float* __restrict__ hid_b2,
    float* __restrict__ out) {
  __shared__ u16 sA[BM][LDA];
  __shared__ u16 sW[DDIM][LDA];
  __shared__ int sI0[BM];     // eg_e / eg_m
  __shared__ int sI1[BM];     // rel
  __shared__ int sI2[BM];     // vi / v_m
  __shared__ float sNA[BM];

  const int tid = threadIdx.x;
  const int lane = tid & 63, wid = tid >> 6;
  const int wr = wid >> 1, wc = wid & 1;
  const int l16 = lane & 15, l4 = lane >> 4;
  const int j0 = blockIdx.x * BM;

  const u16* WT_msg1 = g_WT + OFF_MSG1;
  const u16* WT_msg2 = g_WT + OFF_MSG2;
  const u16* WT_hid1 = g_WT + OFF_HID1;
  const u16* WT_hid2 = g_WT + OFF_HID2;

  float mb1v[4], mb2v[4], hb1v[4], hb2v[4];
#pragma unroll
  for (int nr = 0; nr < 4; ++nr) {
    int col = wc * 64 + nr * 16 + l16;
    mb1v[nr] = msg_b1[col]; mb2v[nr] = msg_b2[col];
    hb1v[nr] = hid_b1[col]; hb2v[nr] = hid_b2[col];
  }

  const f32x4 zero4 = {0.f, 0.f, 0.f, 0.f};
  f32x4 aggr[4][4];
#pragma unroll
  for (int a = 0; a < 4; ++a)
#pragma unroll
    for (int b = 0; b < 4; ++b) aggr[a][b] = zero4;

  // ================= edge-message phase: 4 tiles of 128 edges =================
#pragma unroll 1
  for (int t = 0; t < 4; ++t) {
    __syncthreads();
    if (tid < BM) {
      int e = j0 + tid + t * N_MEM_C;
      const int4* se = (const int4*)seen_edges + (size_t)e * 2;
      int4 lo = se[0], hi = se[1];
      sI0[tid] = lo.x;   // eg_e
      sI1[tid] = lo.w;   // rel
      sI2[tid] = hi.z;   // e2vi (col 6)
    }
    __syncthreads();

    f32x4 acc[4][4];
#pragma unroll
    for (int a = 0; a < 4; ++a)
#pragma unroll
      for (int b = 0; b < 4; ++b) acc[a][b] = zero4;

    // chunk 0: hidden[e2vi]
    stage_rows<0>(sA, hidden, sI2, nullptr, 0, N_MEM_C - 1, tid);
    stage_w(sW, WT_msg1, 640, 0, tid);
    __syncthreads();
    gemm128(sA, sW, acc, wr, wc, l16, l4);
    __syncthreads();
    // chunk 1: rel_table[rel]
    stage_rows<0>(sA, rel_table, sI1, nullptr, 0, 499, tid);
    stage_w(sW, WT_msg1, 640, 128, tid);
    __syncthreads();
    gemm128(sA, sW, acc, wr, wc, l16, l4);
    __syncthreads();
    // chunk 2: hidden[j0 + r]  (hidden_vj: segment row itself)
    stage_rows<1>(sA, hidden, nullptr, nullptr, j0, N_MEM_C - 1, tid);
    stage_w(sW, WT_msg1, 640, 256, tid);
    __syncthreads();
    gemm128(sA, sW, acc, wr, wc, l16, l4);
    __syncthreads();
    // chunk 3: query_head_emb[eg]
    stage_rows<0>(sA, qh, sI0, nullptr, 0, 63, tid);
    stage_w(sW, WT_msg1, 640, 384, tid);
    __syncthreads();
    gemm128(sA, sW, acc, wr, wc, l16, l4);
    __syncthreads();
    // chunk 4: query_rel_emb[eg]
    stage_rows<0>(sA, qr, sI0, nullptr, 0, 63, tid);
    stage_w(sW, WT_msg1, 640, 512, tid);
    __syncthreads();
    gemm128(sA, sW, acc, wr, wc, l16, l4);
    __syncthreads();

    // epilogue 1: h = leaky_relu(acc + b1) -> sA (bf16), stage msg_W2
#pragma unroll
    for (int mr = 0; mr < 4; ++mr)
#pragma unroll
      for (int nr = 0; nr < 4; ++nr)
#pragma unroll
        for (int i = 0; i < 4; ++i) {
          float v = acc[mr][nr][i] + mb1v[nr];
          v = (v >= 0.f) ? v : 0.2f * v;
          sA[wr * 64 + mr * 16 + l4 * 4 + i][wc * 64 + nr * 16 + l16] = f2bf(v);
        }
    stage_w(sW, WT_msg2, 128, 0, tid);
    __syncthreads();

    f32x4 acc2[4][4];
#pragma unroll
    for (int a = 0; a < 4; ++a)
#pragma unroll
      for (int b = 0; b < 4; ++b) acc2[a][b] = zero4;
    gemm128(sA, sW, acc2, wr, wc, l16, l4);
#pragma unroll
    for (int mr = 0; mr < 4; ++mr)
#pragma unroll
      for (int nr = 0; nr < 4; ++nr)
#pragma unroll
        for (int i = 0; i < 4; ++i)
          aggr[mr][nr][i] += fast_tanh(acc2[mr][nr][i] + mb2v[nr]);
  }

  // ================= update phase (128 rows j0..j0+127) =================
  __syncthreads();
  if (tid < BM) {
    int m = j0 + tid;
    int2 mn = ((const int2*)memorized)[m];
    int eg = mn.x < 0 ? 0 : (mn.x > 63 ? 63 : mn.x);
    int vm = mn.y < 0 ? 0 : (mn.y > NNODES_C - 1 ? NNODES_C - 1 : mn.y);
    sI0[tid] = eg;
    sI2[tid] = vm;
    sNA[tid] = node_att[(size_t)eg * NNODES_C + vm];
  }

  f32x4 acc[4][4];
#pragma unroll
  for (int a = 0; a < 4; ++a)
#pragma unroll
    for (int b = 0; b < 4; ++b) acc[a][b] = zero4;

  // chunk 0: message_aggr = 0.5 * aggr (from regs, C/D layout -> A-tile layout)
#pragma unroll
  for (int mr = 0; mr < 4; ++mr)
#pragma unroll
    for (int nr = 0; nr < 4; ++nr)
#pragma unroll
      for (int i = 0; i < 4; ++i)
        sA[wr * 64 + mr * 16 + l4 * 4 + i][wc * 64 + nr * 16 + l16] =
            f2bf(0.5f * aggr[mr][nr][i]);
  stage_w(sW, WT_hid1, 640, 0, tid);
  __syncthreads();
  gemm128(sA, sW, acc, wr, wc, l16, l4);
  __syncthreads();
  // chunk 1: hidden[m]
  stage_rows<1>(sA, hidden, nullptr, nullptr, j0, N_MEM_C - 1, tid);
  stage_w(sW, WT_hid1, 640, 128, tid);
  __syncthreads();
  gemm128(sA, sW, acc, wr, wc, l16, l4);
  __syncthreads();
  // chunk 2: na * hidden_uncon[v_m]  (int_W folded into WT_hid1 rows 256..383)
  stage_rows<2>(sA, hidden_uncon, sI2, sNA, 0, NNODES_C - 1, tid);
  stage_w(sW, WT_hid1, 640, 256, tid);
  __syncthreads();
  gemm128(sA, sW, acc, wr, wc, l16, l4);
  __syncthreads();
  // chunk 3: query_head_emb[eg_m]
  stage_rows<0>(sA, qh, sI0, nullptr, 0, 63, tid);
  stage_w(sW, WT_hid1, 640, 384, tid);
  __syncthreads();
  gemm128(sA, sW, acc, wr, wc, l16, l4);
  __syncthreads();
  // chunk 4: query_rel_emb[eg_m]
  stage_rows<0>(sA, qr, sI0, nullptr, 0, 63, tid);
  stage_w(sW, WT_hid1, 640, 512, tid);
  __syncthreads();
  gemm128(sA, sW, acc, wr, wc, l16, l4);
  __syncthreads();

  // epilogue: h -> sA, then GEMM2 with hid_W2, then out = hidden + tanh(.. + b2)
#pragma unroll
  for (int mr = 0; mr < 4; ++mr)
#pragma unroll
    for (int nr = 0; nr < 4; ++nr)
#pragma unroll
      for (int i = 0; i < 4; ++i) {
        float v = acc[mr][nr][i] + hb1v[nr];
        v = (v >= 0.f) ? v : 0.2f * v;
        sA[wr * 64 + mr * 16 + l4 * 4 + i][wc * 64 + nr * 16 + l16] = f2bf(v);
      }
  stage_w(sW, WT_hid2, 128, 0, tid);
  __syncthreads();

  f32x4 acc2[4][4];
#pragma unroll
  for (int a = 0; a < 4; ++a)
#pragma unroll
    for (int b = 0; b < 4; ++b) acc2[a][b] = zero4;
  gemm128(sA, sW, acc2, wr, wc, l16, l4);

#pragma unroll
  for (int mr = 0; mr < 4; ++mr)
#pragma unroll
    for (int nr = 0; nr < 4; ++nr)
#pragma unroll
      for (int i = 0; i < 4; ++i) {
        int row = j0 + wr * 64 + mr * 16 + l4 * 4 + i;
        int col = wc * 64 + nr * 16 + l16;
        size_t o = (size_t)row * DDIM + col;
        out[o] = hidden[o] + fast_tanh(acc2[mr][nr][i] + hb2v[nr]);
      }
}

extern "C" void kernel_launch(void* const* d_in, const int* in_sizes, int n_in,
                              void* d_out, int out_size, void* d_ws, size_t ws_size,
                              hipStream_t stream) {
  (void)in_sizes; (void)n_in; (void)out_size; (void)d_ws; (void)ws_size;
  const float* hidden       = (const float*)d_in[0];
  const int*   seen_edges   = (const int*)d_in[1];
  const int*   memorized    = (const int*)d_in[2];
  const float* node_att     = (const float*)d_in[3];
  const float* hidden_uncon = (const float*)d_in[4];
  const float* qh           = (const float*)d_in[5];
  const float* qr           = (const float*)d_in[6];
  const float* rel_table    = (const float*)d_in[7];
  const float* msg_W1       = (const float*)d_in[8];
  const float* msg_b1       = (const float*)d_in[9];
  const float* msg_W2       = (const float*)d_in[10];
  const float* msg_b2       = (const float*)d_in[11];
  const float* hid_W1       = (const float*)d_in[12];
  const float* hid_b1       = (const float*)d_in[13];
  const float* hid_W2       = (const float*)d_in[14];
  const float* hid_b2       = (const float*)d_in[15];
  const float* int_W        = (const float*)d_in[16];

  prep_transpose<<<dim3(WT_TOTAL / 256), dim3(256), 0, stream>>>(msg_W1, msg_W2, hid_W1, hid_W2);
  prep_weff<<<dim3(64), dim3(256), 0, stream>>>(hid_W1, int_W);
  fused_flow<<<dim3(N_MEM_C / BM), dim3(256), 0, stream>>>(
      hidden, seen_edges, memorized, node_att, hidden_uncon, qh, qr, rel_table,
      msg_b1, msg_b2, hid_b1, hid_b2, (float*)d_out);
}

// Round 5
// 146.458 us; speedup vs baseline: 1.0832x; 1.0832x over previous
//
#include <hip/hip_runtime.h>
#include <hip/hip_bf16.h>

typedef unsigned short u16;
typedef __attribute__((ext_vector_type(8))) short bf16x8;
typedef __attribute__((ext_vector_type(4))) float f32x4;

#define N_MEM_C 65536
#define NNODES_C 50000
#define DDIM 128
#define LDA 136   // 272B rows: breaks power-of-2 bank aliasing
#define BM 128
#define TIL(t) ((t) * 16384)

// bf16 [n][k] weight tiles (128x128 each):
// 0: msg_W1[0:128]^T    (hidden_vi)
// 1: msg_W1[256:384]^T  (hidden_vj)
// 2: msg_W2^T
// 3: hid_W1[0:128]^T    (message_aggr)
// 4: hid_W1[128:256]^T  (hidden)
// 5: (int_W @ hid_W1[256:384])^T   [prep_weff]
// 6: hid_W2^T
__device__ __align__(16) u16 g_WT[7 * 16384];
// f32 gather-add tables
__device__ __align__(16) float g_relW[500 * 128];   // rel_table @ msg_W1[128:256]
__device__ __align__(16) float g_qsumM[64 * 128];   // qh@msg_W1[384:512] + qr@msg_W1[512:640]
__device__ __align__(16) float g_qsumH[64 * 128];   // qh@hid_W1[384:512] + qr@hid_W1[512:640]

__device__ __forceinline__ u16 f2bf_s(float f) {
  __hip_bfloat16 h = __float2bfloat16(f);
  u16 u; __builtin_memcpy(&u, &h, 2);
  return u;
}
__device__ __forceinline__ unsigned pk2(float a, float b) {
  __hip_bfloat162 h = __float22bfloat162_rn(make_float2(a, b));  // v_cvt_pk_bf16_f32
  unsigned u; __builtin_memcpy(&u, &h, 4);
  return u;
}
__device__ __forceinline__ float fast_tanh(float x) {
  float e = __expf(2.0f * x);
  return 1.0f - 2.0f / (e + 1.0f);   // inf-safe
}

// ---- prep: transpose+convert the 6 plain weight tiles ----
extern "C" __global__ void prep_wt(const float* __restrict__ msg_W1,
                                   const float* __restrict__ msg_W2,
                                   const float* __restrict__ hid_W1,
                                   const float* __restrict__ hid_W2) {
  int i = blockIdx.x * 256 + threadIdx.x;   // 6*16384 threads
  int t = i >> 14, idx = i & 16383;
  int n = idx >> 7, k = idx & 127;
  const float* src; int dst;
  switch (t) {
    case 0:  src = msg_W1;             dst = TIL(0); break;
    case 1:  src = msg_W1 + 256 * 128; dst = TIL(1); break;
    case 2:  src = msg_W2;             dst = TIL(2); break;
    case 3:  src = hid_W1;             dst = TIL(3); break;
    case 4:  src = hid_W1 + 128 * 128; dst = TIL(4); break;
    default: src = hid_W2;             dst = TIL(6); break;
  }
  g_WT[dst + n * 128 + k] = f2bf_s(src[k * 128 + n]);
}

// ---- prep: Weff^T = (int_W @ hid_W1[256:384])^T into tile 5 ----
extern "C" __global__ void prep_weff(const float* __restrict__ hid_W1,
                                     const float* __restrict__ int_W) {
  int i = blockIdx.x * 256 + threadIdx.x;   // 16384
  int n = i & 127, q = i >> 7;
  float s = 0.f;
  for (int p = 0; p < 128; ++p)
    s += int_W[q * 128 + p] * hid_W1[(256 + p) * 128 + n];
  g_WT[TIL(5) + n * 128 + q] = f2bf_s(s);
}

// ---- prep: relW[r][n] = sum_k rel_table[r][k] * msg_W1[128+k][n] ----
extern "C" __global__ void prep_relW(const float* __restrict__ rel_table,
                                     const float* __restrict__ msg_W1) {
  int i = blockIdx.x * 256 + threadIdx.x;   // 64000
  if (i >= 500 * 128) return;
  int r = i >> 7, n = i & 127;
  float s = 0.f;
  for (int k = 0; k < 128; ++k)
    s += rel_table[r * 128 + k] * msg_W1[(128 + k) * 128 + n];
  g_relW[i] = s;
}

// ---- prep: per-batch query contributions for both MLPs ----
extern "C" __global__ void prep_qsum(const float* __restrict__ qh,
                                     const float* __restrict__ qr,
                                     const float* __restrict__ msg_W1,
                                     const float* __restrict__ hid_W1) {
  int i = blockIdx.x * 256 + threadIdx.x;   // 8192
  int g = i >> 7, n = i & 127;
  float sM = 0.f, sH = 0.f;
  for (int k = 0; k < 128; ++k) {
    float h = qh[g * 128 + k], r = qr[g * 128 + k];
    sM += h * msg_W1[(384 + k) * 128 + n] + r * msg_W1[(512 + k) * 128 + n];
    sH += h * hid_W1[(384 + k) * 128 + n] + r * hid_W1[(512 + k) * 128 + n];
  }
  g_qsumM[i] = sM;
  g_qsumH[i] = sH;
}

// ---- staging: gather f32 rows -> bf16 LDS tile ----
// MODE 0: idx from array; MODE 1: idx = base + r; MODE 2: idx from array, scaled
template <int MODE>
__device__ __forceinline__ void stage_rows(u16 (*A)[LDA], const float* __restrict__ src,
                                           const int* idxArr, const float* scArr,
                                           int base, int tid) {
#pragma unroll
  for (int it = 0; it < 4; ++it) {
    int slot = it * 256 + tid;          // 1024 slots = 128 rows x 8 (16 floats)
    int r = slot >> 3, seg = slot & 7;
    int idx = (MODE == 1) ? (base + r) : idxArr[r];
    float sc = (MODE == 2) ? scArr[r] : 1.0f;
    const float4* p = (const float4*)(src + (size_t)idx * DDIM + seg * 16);
    float4 f0 = p[0], f1 = p[1], f2 = p[2], f3 = p[3];
    if (MODE == 2) {
      f0.x *= sc; f0.y *= sc; f0.z *= sc; f0.w *= sc;
      f1.x *= sc; f1.y *= sc; f1.z *= sc; f1.w *= sc;
      f2.x *= sc; f2.y *= sc; f2.z *= sc; f2.w *= sc;
      f3.x *= sc; f3.y *= sc; f3.z *= sc; f3.w *= sc;
    }
    uint4* q = (uint4*)&A[r][seg * 16];
    q[0] = make_uint4(pk2(f0.x, f0.y), pk2(f0.z, f0.w), pk2(f1.x, f1.y), pk2(f1.z, f1.w));
    q[1] = make_uint4(pk2(f2.x, f2.y), pk2(f2.z, f2.w), pk2(f3.x, f3.y), pk2(f3.z, f3.w));
  }
}

// stage one 128x128 bf16 W tile (ldk = 128)
__device__ __forceinline__ void stage_w(u16 (*W)[LDA], const u16* __restrict__ WT, int tid) {
#pragma unroll
  for (int it = 0; it < 2; ++it) {
    int slot = it * 256 + tid;          // 512 slots = 128 rows x 4 (32 u16)
    int n = slot >> 2, seg = slot & 3;
    const uint4* p = (const uint4*)(WT + n * 128 + seg * 32);
    uint4 a = p[0], b = p[1], c = p[2], d = p[3];
    uint4* q = (uint4*)&W[n][seg * 32];
    q[0] = a; q[1] = b; q[2] = c; q[3] = d;
  }
}

__device__ __forceinline__ void gemm128(const u16 (*A)[LDA], const u16 (*W)[LDA],
                                        f32x4 (&acc)[4][4], int wr, int wc, int l16, int l4) {
#pragma unroll
  for (int ks = 0; ks < 4; ++ks) {
    bf16x8 av[4], bv[4];
#pragma unroll
    for (int mr = 0; mr < 4; ++mr)
      av[mr] = *(const bf16x8*)&A[wr * 64 + mr * 16 + l16][ks * 32 + l4 * 8];
#pragma unroll
    for (int nr = 0; nr < 4; ++nr)
      bv[nr] = *(const bf16x8*)&W[wc * 64 + nr * 16 + l16][ks * 32 + l4 * 8];
#pragma unroll
    for (int mr = 0; mr < 4; ++mr)
#pragma unroll
      for (int nr = 0; nr < 4; ++nr)
        acc[mr][nr] = __builtin_amdgcn_mfma_f32_16x16x32_bf16(av[mr], bv[nr], acc[mr][nr], 0, 0, 0);
  }
}

extern "C" __global__ __launch_bounds__(256, 2) void fused_flow(
    const float* __restrict__ hidden, const int* __restrict__ seen_edges,
    const int* __restrict__ memorized, const float* __restrict__ node_att,
    const float* __restrict__ hidden_uncon,
    const float* __restrict__ msg_b1, const float* __restrict__ msg_b2,
    const float* __restrict__ hid_b1, const float* __restrict__ hid_b2,
    float* __restrict__ out) {
  __shared__ u16 sA[BM][LDA];
  __shared__ u16 sW[DDIM][LDA];
  __shared__ int sI0[BM];     // eg
  __shared__ int sI1[BM];     // rel
  __shared__ int sI2[BM];     // vi / v_m
  __shared__ float sNA[BM];

  const int tid = threadIdx.x;
  const int lane = tid & 63, wid = tid >> 6;
  const int wr = wid >> 1, wc = wid & 1;
  const int l16 = lane & 15, l4 = lane >> 4;
  const int j0 = blockIdx.x * BM;

  float mb1v[4], mb2v[4], hb1v[4], hb2v[4];
#pragma unroll
  for (int nr = 0; nr < 4; ++nr) {
    int col = wc * 64 + nr * 16 + l16;
    mb1v[nr] = msg_b1[col]; mb2v[nr] = msg_b2[col];
    hb1v[nr] = hid_b1[col]; hb2v[nr] = hid_b2[col];
  }

  const f32x4 zero4 = {0.f, 0.f, 0.f, 0.f};

  // ---- phase V: hidden_vj chunk, shared by all 4 edge tiles ----
  stage_rows<1>(sA, hidden, nullptr, nullptr, j0, tid);
  stage_w(sW, g_WT + TIL(1), tid);
  __syncthreads();
  f32x4 acc_vj[4][4];
#pragma unroll
  for (int a = 0; a < 4; ++a)
#pragma unroll
    for (int b = 0; b < 4; ++b) acc_vj[a][b] = zero4;
  gemm128(sA, sW, acc_vj, wr, wc, l16, l4);

  f32x4 aggr[4][4];
#pragma unroll
  for (int a = 0; a < 4; ++a)
#pragma unroll
    for (int b = 0; b < 4; ++b) aggr[a][b] = zero4;

  // ---- edge-message phase: 4 tiles of 128 edges ----
#pragma unroll 1
  for (int t = 0; t < 4; ++t) {
    __syncthreads();                    // everyone done reading sA/sW
    if (tid < BM) {
      int e = j0 + tid + t * N_MEM_C;
      const int4* se = (const int4*)seen_edges + (size_t)e * 2;
      int4 lo = se[0], hi = se[1];
      int eg = min(max(lo.x, 0), 63);
      int rl = min(max(lo.w, 0), 499);
      int vi = min(max(hi.z, 0), N_MEM_C - 1);
      sI0[tid] = eg; sI1[tid] = rl; sI2[tid] = vi;
    }
    __syncthreads();

    // chunk 0: hidden[e2vi] GEMM (acc starts from the vj contribution)
    stage_rows<0>(sA, hidden, sI2, nullptr, 0, tid);
    stage_w(sW, g_WT + TIL(0), tid);
    __syncthreads();
    f32x4 acc[4][4];
#pragma unroll
    for (int a = 0; a < 4; ++a)
#pragma unroll
      for (int b = 0; b < 4; ++b) acc[a][b] = acc_vj[a][b];
    gemm128(sA, sW, acc, wr, wc, l16, l4);

    // gather-add: rel chunk + (qh,qr) chunks from precomputed f32 tables
#pragma unroll
    for (int mr = 0; mr < 4; ++mr)
#pragma unroll
      for (int i = 0; i < 4; ++i) {
        int r = wr * 64 + mr * 16 + l4 * 4 + i;
        const float* pr = g_relW + sI1[r] * 128;
        const float* pq = g_qsumM + sI0[r] * 128;
#pragma unroll
        for (int nr = 0; nr < 4; ++nr) {
          int c = wc * 64 + nr * 16 + l16;
          acc[mr][nr][i] += pr[c] + pq[c];
        }
      }
    __syncthreads();                    // all waves done reading sA/sW

    // epilogue 1: h = leaky_relu(acc + b1) -> sA, stage msg_W2
#pragma unroll
    for (int mr = 0; mr < 4; ++mr)
#pragma unroll
      for (int nr = 0; nr < 4; ++nr)
#pragma unroll
        for (int i = 0; i < 4; ++i) {
          float v = acc[mr][nr][i] + mb1v[nr];
          v = (v >= 0.f) ? v : 0.2f * v;
          sA[wr * 64 + mr * 16 + l4 * 4 + i][wc * 64 + nr * 16 + l16] = f2bf_s(v);
        }
    stage_w(sW, g_WT + TIL(2), tid);
    __syncthreads();

    f32x4 acc2[4][4];
#pragma unroll
    for (int a = 0; a < 4; ++a)
#pragma unroll
      for (int b = 0; b < 4; ++b) acc2[a][b] = zero4;
    gemm128(sA, sW, acc2, wr, wc, l16, l4);
#pragma unroll
    for (int mr = 0; mr < 4; ++mr)
#pragma unroll
      for (int nr = 0; nr < 4; ++nr)
#pragma unroll
        for (int i = 0; i < 4; ++i)
          aggr[mr][nr][i] += fast_tanh(acc2[mr][nr][i] + mb2v[nr]);
  }

  // ---- update phase ----
  __syncthreads();
  if (tid < BM) {
    int2 mn = ((const int2*)memorized)[j0 + tid];
    int eg = min(max(mn.x, 0), 63);
    int vm = min(max(mn.y, 0), NNODES_C - 1);
    sI0[tid] = eg; sI2[tid] = vm;
    sNA[tid] = node_att[(size_t)eg * NNODES_C + vm];
  }
  // chunk 0: message_aggr = 0.5 * aggr -> sA
#pragma unroll
  for (int mr = 0; mr < 4; ++mr)
#pragma unroll
    for (int nr = 0; nr < 4; ++nr)
#pragma unroll
      for (int i = 0; i < 4; ++i)
        sA[wr * 64 + mr * 16 + l4 * 4 + i][wc * 64 + nr * 16 + l16] =
            f2bf_s(0.5f * aggr[mr][nr][i]);
  stage_w(sW, g_WT + TIL(3), tid);
  __syncthreads();
  f32x4 accU[4][4];
#pragma unroll
  for (int a = 0; a < 4; ++a)
#pragma unroll
    for (int b = 0; b < 4; ++b) accU[a][b] = zero4;
  gemm128(sA, sW, accU, wr, wc, l16, l4);
  __syncthreads();

  // chunk 1: hidden[m]
  stage_rows<1>(sA, hidden, nullptr, nullptr, j0, tid);
  stage_w(sW, g_WT + TIL(4), tid);
  __syncthreads();
  gemm128(sA, sW, accU, wr, wc, l16, l4);
  __syncthreads();

  // chunk 2: na * hidden_uncon[v_m] @ Weff
  stage_rows<2>(sA, hidden_uncon, sI2, sNA, 0, tid);
  stage_w(sW, g_WT + TIL(5), tid);
  __syncthreads();
  gemm128(sA, sW, accU, wr, wc, l16, l4);

  // gather-add: query chunks for the update MLP
#pragma unroll
  for (int mr = 0; mr < 4; ++mr)
#pragma unroll
    for (int i = 0; i < 4; ++i) {
      int r = wr * 64 + mr * 16 + l4 * 4 + i;
      const float* pq = g_qsumH + sI0[r] * 128;
#pragma unroll
      for (int nr = 0; nr < 4; ++nr)
        accU[mr][nr][i] += pq[wc * 64 + nr * 16 + l16];
    }
  __syncthreads();

  // epilogue 2: h -> sA, GEMM with hid_W2, out = hidden + tanh(.. + b2)
#pragma unroll
  for (int mr = 0; mr < 4; ++mr)
#pragma unroll
    for (int nr = 0; nr < 4; ++nr)
#pragma unroll
      for (int i = 0; i < 4; ++i) {
        float v = accU[mr][nr][i] + hb1v[nr];
        v = (v >= 0.f) ? v : 0.2f * v;
        sA[wr * 64 + mr * 16 + l4 * 4 + i][wc * 64 + nr * 16 + l16] = f2bf_s(v);
      }
  stage_w(sW, g_WT + TIL(6), tid);
  __syncthreads();

  f32x4 acc2[4][4];
#pragma unroll
  for (int a = 0; a < 4; ++a)
#pragma unroll
    for (int b = 0; b < 4; ++b) acc2[a][b] = zero4;
  gemm128(sA, sW, acc2, wr, wc, l16, l4);

#pragma unroll
  for (int mr = 0; mr < 4; ++mr)
#pragma unroll
    for (int nr = 0; nr < 4; ++nr)
#pragma unroll
      for (int i = 0; i < 4; ++i) {
        int row = j0 + wr * 64 + mr * 16 + l4 * 4 + i;
        int col = wc * 64 + nr * 16 + l16;
        size_t o = (size_t)row * DDIM + col;
        out[o] = hidden[o] + fast_tanh(acc2[mr][nr][i] + hb2v[nr]);
      }
}

extern "C" void kernel_launch(void* const* d_in, const int* in_sizes, int n_in,
                              void* d_out, int out_size, void* d_ws, size_t ws_size,
                              hipStream_t stream) {
  (void)in_sizes; (void)n_in; (void)out_size; (void)d_ws; (void)ws_size;
  const float* hidden       = (const float*)d_in[0];
  const int*   seen_edges   = (const int*)d_in[1];
  const int*   memorized    = (const int*)d_in[2];
  const float* node_att     = (const float*)d_in[3];
  const float* hidden_uncon = (const float*)d_in[4];
  const float* qh           = (const float*)d_in[5];
  const float* qr           = (const float*)d_in[6];
  const float* rel_table    = (const float*)d_in[7];
  const float* msg_W1       = (const float*)d_in[8];
  const float* msg_b1       = (const float*)d_in[9];
  const float* msg_W2       = (const float*)d_in[10];
  const float* msg_b2       = (const float*)d_in[11];
  const float* hid_W1       = (const float*)d_in[12];
  const float* hid_b1       = (const float*)d_in[13];
  const float* hid_W2       = (const float*)d_in[14];
  const float* hid_b2       = (const float*)d_in[15];
  const float* int_W        = (const float*)d_in[16];

  prep_wt<<<dim3(6 * 16384 / 256), dim3(256), 0, stream>>>(msg_W1, msg_W2, hid_W1, hid_W2);
  prep_weff<<<dim3(64), dim3(256), 0, stream>>>(hid_W1, int_W);
  prep_relW<<<dim3(250), dim3(256), 0, stream>>>(rel_table, msg_W1);
  prep_qsum<<<dim3(32), dim3(256), 0, stream>>>(qh, qr, msg_W1, hid_W1);
  fused_flow<<<dim3(N_MEM_C / BM), dim3(256), 0, stream>>>(
      hidden, seen_edges, memorized, node_att, hidden_uncon,
      msg_b1, msg_b2, hid_b1, hid_b2, (float*)d_out);
}